// Round 1
// baseline (99.841 us; speedup 1.0000x reference)
//
#include <hip/hip_runtime.h>

#define NUM_CLASSES 256
#define CLAMP_MIN_F (-10.0f)

// One wave (64 lanes) per row; lane l loads float4 covering cols 4l..4l+3.
// Per-thread fp32 row partial -> double accumulator -> block reduce ->
// deterministic per-block partial in d_ws (double). No float atomics.
__global__ __launch_bounds__(256) void ordloss_main(
    const float* __restrict__ logits,
    const int* __restrict__ targets,
    double* __restrict__ partials,
    int batch)
{
    const int lane          = threadIdx.x & 63;
    const int wave_in_block = threadIdx.x >> 6;
    const int waves_per_blk = blockDim.x >> 6;
    const int global_wave   = blockIdx.x * waves_per_blk + wave_in_block;
    const int total_waves   = gridDim.x * waves_per_blk;
    const int j0            = lane * 4;

    double acc = 0.0;

    for (int row = global_wave; row < batch; row += total_waves) {
        const int t = targets[row];                       // wave-uniform
        const bool t_not_last = (t < NUM_CLASSES - 1);
        const float4 v4 =
            reinterpret_cast<const float4*>(logits + (size_t)row * NUM_CLASSES)[lane];

        float vv[4] = {v4.x, v4.y, v4.z, v4.w};
        float s = 0.0f;
        #pragma unroll
        for (int e = 0; e < 4; ++e) {
            const int j   = j0 + e;
            const float v = vv[e];
            const float c1 = fmaxf(v, CLAMP_MIN_F);        // term1 (j <  t)
            const float c2 = fmaxf(-v, CLAMP_MIN_F);       // term2 (j >= t)
            const float contrib = (j < t) ? c1 : (t_not_last ? c2 : 0.0f);
            s += contrib;
        }
        acc += (double)s;
    }

    // wave reduction (64 lanes) in double
    #pragma unroll
    for (int off = 32; off > 0; off >>= 1)
        acc += __shfl_down(acc, off, 64);

    __shared__ double lds[8];  // up to 8 waves/block (we use 4)
    if (lane == 0) lds[wave_in_block] = acc;
    __syncthreads();

    if (threadIdx.x == 0) {
        double b = 0.0;
        for (int w = 0; w < waves_per_blk; ++w) b += lds[w];
        partials[blockIdx.x] = b;
    }
}

__global__ __launch_bounds__(256) void ordloss_final(
    const double* __restrict__ partials, int nparts,
    float* __restrict__ out, double inv_batch)
{
    __shared__ double lds[256];
    double a = 0.0;
    for (int i = threadIdx.x; i < nparts; i += 256) a += partials[i];
    lds[threadIdx.x] = a;
    __syncthreads();
    for (int s = 128; s > 0; s >>= 1) {
        if (threadIdx.x < s) lds[threadIdx.x] += lds[threadIdx.x + s];
        __syncthreads();
    }
    if (threadIdx.x == 0) out[0] = (float)(lds[0] * inv_batch);
}

extern "C" void kernel_launch(void* const* d_in, const int* in_sizes, int n_in,
                              void* d_out, int out_size, void* d_ws, size_t ws_size,
                              hipStream_t stream) {
    const float* logits  = (const float*)d_in[0];
    const int*   targets = (const int*)d_in[1];
    float*       out     = (float*)d_out;
    const int    batch   = in_sizes[1];   // 524288 rows

    double* partials = (double*)d_ws;     // 2048 doubles = 16 KB << ws_size
    const int nblocks = 2048;             // 8192 waves -> 64 rows/wave grid-stride

    ordloss_main<<<nblocks, 256, 0, stream>>>(logits, targets, partials, batch);
    ordloss_final<<<1, 256, 0, stream>>>(partials, nblocks, out, 1.0 / (double)batch);
}